// Round 16
// baseline (807.250 us; speedup 1.0000x reference)
//
#include <hip/hip_runtime.h>

#define TT 512   // sequence length
#define BB 64    // batch
#define HH 128   // hidden
#define G4 512   // 4*H
#define PF 4     // prefetch ring depth == out-chunk size (even, divides TT)

typedef short bf16x8 __attribute__((ext_vector_type(8)));
typedef short s16x4  __attribute__((ext_vector_type(4)));
typedef float f32x4  __attribute__((ext_vector_type(4)));
typedef _Float16 f16x8v __attribute__((ext_vector_type(8)));

__device__ __forceinline__ unsigned short f2bf(float x) {
    unsigned u = __float_as_uint(x);
    u += 0x7fff + ((u >> 16) & 1);           // RNE
    return (unsigned short)(u >> 16);
}
__device__ __forceinline__ float bf2f(unsigned short h) {
    return __uint_as_float(((unsigned)h) << 16);
}

// ---------------- fp32 -> bf16 hi/lo split (memory-bound) ----------------
__global__ __launch_bounds__(256) void convert_hilo(
    const float4* __restrict__ src, s16x4* __restrict__ hi,
    s16x4* __restrict__ lo, int n4)
{
    for (int i = blockIdx.x * 256 + threadIdx.x; i < n4; i += gridDim.x * 256) {
        float4 f = src[i];
        float fa[4] = {f.x, f.y, f.z, f.w};
        s16x4 h, l;
        #pragma unroll
        for (int e = 0; e < 4; ++e) {
            unsigned short hh = f2bf(fa[e]);
            h[e] = (short)hh;
            l[e] = (short)f2bf(fa[e] - bf2f(hh));
        }
        hi[i] = h;
        lo[i] = l;
    }
}

// ---------------- MFMA pre-GEMM v2 (proven R6-R15): A pre-split, W in-kernel ----
template<int K>
__global__ __launch_bounds__(256) void gemm_mfma2(
    const short* __restrict__ Ahi, const short* __restrict__ Alo,
    const float* __restrict__ W,
    const float* __restrict__ b0, const float* __restrict__ b1,
    float* __restrict__ C)
{
    constexpr int NC  = K / 32;
    constexpr int LDA = 40;                  // shorts per staged row (32 + 8 pad)
    __shared__ short Ahi_s[128 * LDA], Alo_s[128 * LDA];
    __shared__ short Whi_s[128 * LDA], Wlo_s[128 * LDA];

    const int bm  = blockIdx.x * 128;
    const int bn  = blockIdx.y * 128;
    const int tid = threadIdx.x;
    const int wv  = tid >> 6;
    const int l   = tid & 63;
    const int jl  = l & 15;
    const int rg  = l >> 4;
    const int wr  = wv >> 1;
    const int wc  = wv & 1;

    const int sr = tid >> 1;
    const int sc = (tid & 1) * 16;

    const short* Aph = Ahi + (size_t)(bm + sr) * K + sc;
    const short* Apl = Alo + (size_t)(bm + sr) * K + sc;
    const float* Wp  = W   + (size_t)(bn + sr) * K + sc;

    f32x4 acc[4][4];
    #pragma unroll
    for (int i = 0; i < 4; ++i)
        #pragma unroll
        for (int j = 0; j < 4; ++j)
            acc[i][j] = (f32x4){0.f, 0.f, 0.f, 0.f};

    bf16x8 pah[2], pal[2];
    float4 pw[4];
    pah[0] = *(const bf16x8*)(Aph);
    pah[1] = *(const bf16x8*)(Aph + 8);
    pal[0] = *(const bf16x8*)(Apl);
    pal[1] = *(const bf16x8*)(Apl + 8);
    #pragma unroll
    for (int q = 0; q < 4; ++q) pw[q] = *(const float4*)(Wp + q * 4);

    #pragma unroll 1
    for (int c = 0; c < NC; ++c) {
        __syncthreads();
        {
            int off = sr * LDA + sc;
            *(bf16x8*)&Ahi_s[off]     = pah[0];
            *(bf16x8*)&Ahi_s[off + 8] = pah[1];
            *(bf16x8*)&Alo_s[off]     = pal[0];
            *(bf16x8*)&Alo_s[off + 8] = pal[1];
            #pragma unroll
            for (int q = 0; q < 4; ++q) {
                float fw[4] = {pw[q].x, pw[q].y, pw[q].z, pw[q].w};
                s16x4 h, lo4;
                #pragma unroll
                for (int e = 0; e < 4; ++e) {
                    unsigned short hh = f2bf(fw[e]);
                    h[e]   = (short)hh;
                    lo4[e] = (short)f2bf(fw[e] - bf2f(hh));
                }
                *(s16x4*)&Whi_s[off + q * 4] = h;
                *(s16x4*)&Wlo_s[off + q * 4] = lo4;
            }
        }
        __syncthreads();
        if (c + 1 < NC) {
            pah[0] = *(const bf16x8*)(Aph + (c + 1) * 32);
            pah[1] = *(const bf16x8*)(Aph + (c + 1) * 32 + 8);
            pal[0] = *(const bf16x8*)(Apl + (c + 1) * 32);
            pal[1] = *(const bf16x8*)(Apl + (c + 1) * 32 + 8);
            #pragma unroll
            for (int q = 0; q < 4; ++q)
                pw[q] = *(const float4*)(Wp + (c + 1) * 32 + q * 4);
        }
        bf16x8 ah[4], al[4], wh[4], wl[4];
        #pragma unroll
        for (int t = 0; t < 4; ++t) {
            int ra = (wr * 64 + t * 16 + jl) * LDA + rg * 8;
            ah[t] = *(const bf16x8*)&Ahi_s[ra];
            al[t] = *(const bf16x8*)&Alo_s[ra];
            int rw = (wc * 64 + t * 16 + jl) * LDA + rg * 8;
            wh[t] = *(const bf16x8*)&Whi_s[rw];
            wl[t] = *(const bf16x8*)&Wlo_s[rw];
        }
        #pragma unroll
        for (int tm = 0; tm < 4; ++tm)
            #pragma unroll
            for (int tn = 0; tn < 4; ++tn) {
                acc[tm][tn] = __builtin_amdgcn_mfma_f32_16x16x32_bf16(ah[tm], wh[tn], acc[tm][tn], 0, 0, 0);
                acc[tm][tn] = __builtin_amdgcn_mfma_f32_16x16x32_bf16(ah[tm], wl[tn], acc[tm][tn], 0, 0, 0);
                acc[tm][tn] = __builtin_amdgcn_mfma_f32_16x16x32_bf16(al[tm], wh[tn], acc[tm][tn], 0, 0, 0);
            }
    }

    // epilogue: C layout col=lane&15 (n), row=(lane>>4)*4+r (m)
    #pragma unroll
    for (int tn = 0; tn < 4; ++tn) {
        int n = bn + wc * 64 + tn * 16 + jl;
        float bias = b0[n] + b1[n];
        #pragma unroll
        for (int tm = 0; tm < 4; ++tm) {
            int m = bm + wr * 64 + tm * 16 + rg * 4;
            #pragma unroll
            for (int r = 0; r < 4; ++r)
                C[(size_t)(m + r) * G4 + n] = acc[tm][tn][r] + bias;
        }
    }
}

// ---------------- LSTM scan v13: per-seq MFMA recurrence, 4 waves ----------------
// 128 blocks = 2dir x 64batch (1 seq each), 256 thr (4 waves, 1 wave/SIMD).
// Same math as v12 (R15-proven: absmax 9.77e-4) but 4 waves: per-SIMD MFMA
// pipe unchanged (32 MFMA = ~620 cyc) while LDS A-reads 32->16/step, tail
// wave-issue 8->4, refill vmem 32->16, barrier 512->256 thr. MFMA ILP (8
// independent acc chains/wave) keeps the pipe fed at 1 wave/SIMD.
// Wave w covers cells [w*32, w*32+32): gate tiles (cc, tt) at rows
// cc*128 + w*32 + tt*16 + (lane&15), cc=0..3, tt=0..1; x 4 k-chunks = 32 MFMA.
// A (h) rows 1-15 junk (unread); C row 0 only. Tail: lanes 0-15, 2 cells each.
__global__ __launch_bounds__(256, 1) void lstm_scan_v13(
    const float* __restrict__ pre_f, const float* __restrict__ pre_b,
    const float* __restrict__ whh_f, const float* __restrict__ whh_b,
    float* __restrict__ out)
{
    const int dir = blockIdx.x >> 6;
    const int b   = blockIdx.x & 63;
    const float* __restrict__ pre  = dir ? pre_b : pre_f;
    const float* __restrict__ w_hh = dir ? whh_b : whh_f;

    const int tid = threadIdx.x;
    const int w   = tid >> 6;        // wave 0..3
    const int l   = tid & 63;
    const int jl  = l & 15;
    const int rg  = l >> 4;          // 0..3

    __shared__ _Float16 h_lds[2][HH];
    __shared__ float oring[2][PF][HH];

    // B fragments: rows cc*128 + w*32 + tt*16 + jl, k = kc*32 + rg*8 + e
    f16x8v bw[4][2][4];
    #pragma unroll
    for (int cc = 0; cc < 4; ++cc)
        #pragma unroll
        for (int tt = 0; tt < 2; ++tt) {
            const float* wr_ = w_hh + (size_t)(cc * HH + w * 32 + tt * 16 + jl) * HH + rg * 8;
            #pragma unroll
            for (int kc = 0; kc < 4; ++kc) {
                const float* p_ = wr_ + kc * 32;
                f16x8v f;
                #pragma unroll
                for (int e = 0; e < 8; ++e) f[e] = (_Float16)p_[e];
                bw[cc][tt][kc] = f;
            }
        }

    if (tid < 2 * HH) ((_Float16*)h_lds)[tid] = (_Float16)0.f;

    // pre ring: lane pattern repeats every 16 lanes; only lanes 0-15 consumed
    const size_t base = (size_t)b * TT * G4 + w * 32 + jl;
    float pf[PF][4][2];
    #pragma unroll
    for (int u = 0; u < PF; ++u) {
        int tau = dir ? (TT - 1 - u) : u;
        #pragma unroll
        for (int cc = 0; cc < 4; ++cc)
            #pragma unroll
            for (int tt = 0; tt < 2; ++tt)
                pf[u][cc][tt] = pre[base + (size_t)tau * G4 + cc * HH + tt * 16];
    }

    float cst[2] = {0.f, 0.f};
    const float ASIG = -1.4426950408889634f;  // -log2(e)
    const float ATAN =  2.8853900817779268f;  // 2*log2(e)

    const int s_loc = tid >> 6;      // 0..3 (PF=4)
    const int c64   = tid & 63;

    __syncthreads();

    for (int s0 = 0; s0 < TT; s0 += PF) {
        const int p = (s0 >> 2) & 1;          // oring parity for this chunk
        #pragma unroll
        for (int u = 0; u < PF; ++u) {
            const int s = s0 + u;
            const int cur = u & 1;            // parity(s) == parity(u)

            // A fragments: wave-uniform per rg-group; rows 1-15 junk (unread)
            f16x8v a[4];
            #pragma unroll
            for (int kc = 0; kc < 4; ++kc)
                a[kc] = *(const f16x8v*)&h_lds[cur][kc * 32 + rg * 8];

            // C init from pre (row 0 real; junk rows harmless), pv BEFORE refill
            f32x4 acc[4][2];
            #pragma unroll
            for (int cc = 0; cc < 4; ++cc)
                #pragma unroll
                for (int tt = 0; tt < 2; ++tt)
                    acc[cc][tt] = (f32x4){pf[u][cc][tt], 0.f, 0.f, 0.f};

            // ring refill (clamped; full-chunk window to hide HBM latency)
            {
                int sn = s + PF;
                int taun = dir ? (TT - 1 - sn) : sn;
                taun = taun < 0 ? 0 : (taun > TT - 1 ? TT - 1 : taun);
                #pragma unroll
                for (int cc = 0; cc < 4; ++cc)
                    #pragma unroll
                    for (int tt = 0; tt < 2; ++tt)
                        pf[u][cc][tt] = pre[base + (size_t)taun * G4 + cc * HH + tt * 16];
            }

            // 32 MFMA: 8 independent acc chains x 4-deep k
            #pragma unroll
            for (int cc = 0; cc < 4; ++cc)
                #pragma unroll
                for (int tt = 0; tt < 2; ++tt)
                    #pragma unroll
                    for (int kc = 0; kc < 4; ++kc)
                        acc[cc][tt] = __builtin_amdgcn_mfma_f32_16x16x32_f16(
                            a[kc], bw[cc][tt][kc], acc[cc][tt], 0, 0, 0);

            // tail: lanes 0-15 hold cells w*32 + tt*16 + l in acc[cc][tt][0]
            if (l < 16) {
                #pragma unroll
                for (int tt = 0; tt < 2; ++tt) {
                    float gi = acc[0][tt][0], gf = acc[1][tt][0];
                    float gg = acc[2][tt][0], go = acc[3][tt][0];
                    float ei = __builtin_amdgcn_exp2f(ASIG * gi);
                    float si = __builtin_amdgcn_rcpf(1.f + ei);
                    float ef = __builtin_amdgcn_exp2f(ASIG * gf);
                    float sf = __builtin_amdgcn_rcpf(1.f + ef);
                    float eg = __builtin_amdgcn_exp2f(ATAN * gg);
                    float tg = 1.f - 2.f * __builtin_amdgcn_rcpf(1.f + eg);
                    float eo = __builtin_amdgcn_exp2f(ASIG * go);
                    float so = __builtin_amdgcn_rcpf(1.f + eo);
                    float c  = fmaf(sf, cst[tt], si * tg);
                    cst[tt] = c;
                    float e2 = __builtin_amdgcn_exp2f(ATAN * c);
                    float h  = so * (1.f - 2.f * __builtin_amdgcn_rcpf(1.f + e2));
                    int j = w * 32 + tt * 16 + l;
                    h_lds[cur ^ 1][j] = (_Float16)h;
                    oring[p][u][j] = h;
                }
            }
            __syncthreads();
        }

        // coalesced burst-write of the finished chunk (opposite parity next
        // chunk; >=2 barriers separate reuse of this half -> race-free)
        {
            int sb = s0 + s_loc;
            int tau = dir ? (TT - 1 - sb) : sb;
            float* orow = out + ((size_t)b * TT + tau) * (2 * HH) + dir * HH;
            orow[c64]      = oring[p][s_loc][c64];
            orow[c64 + 64] = oring[p][s_loc][c64 + 64];
        }
    }
}

// ---------------- FC v2 (proven R7) ----------------
__global__ __launch_bounds__(256) void fc_v2(
    const float* __restrict__ h2, const float* __restrict__ w_fc,
    const float* __restrict__ b_fc, float* __restrict__ out)
{
    __shared__ float4 wsT[64][64];          // [k4][n]
    const int tid = threadIdx.x;
    const int bm  = blockIdx.x * 64;
    const int n   = tid & 63;
    const int mg  = tid >> 6;

    #pragma unroll
    for (int qq = 0; qq < 16; ++qq) {
        int id = qq * 256 + tid;
        int nn = id >> 6, k4 = id & 63;
        wsT[k4][nn] = *(const float4*)&w_fc[(size_t)nn * 256 + k4 * 4];
    }
    __syncthreads();

    const float bias = b_fc[n];
    const float* hrow = h2 + (size_t)(bm + mg * 16) * 256;

    float acc[16];
    #pragma unroll
    for (int mi = 0; mi < 16; ++mi) acc[mi] = 0.f;

    #pragma unroll 2
    for (int k4 = 0; k4 < 64; ++k4) {
        float4 w4 = wsT[k4][n];
        #pragma unroll
        for (int mi = 0; mi < 16; ++mi) {
            float4 h4 = *(const float4*)(hrow + (size_t)mi * 256 + k4 * 4);
            acc[mi] = fmaf(h4.x, w4.x, acc[mi]);
            acc[mi] = fmaf(h4.y, w4.y, acc[mi]);
            acc[mi] = fmaf(h4.z, w4.z, acc[mi]);
            acc[mi] = fmaf(h4.w, w4.w, acc[mi]);
        }
    }
    #pragma unroll
    for (int mi = 0; mi < 16; ++mi)
        out[(size_t)(bm + mg * 16 + mi) * 64 + n] = acc[mi] + bias;
}

extern "C" void kernel_launch(void* const* d_in, const int* in_sizes, int n_in,
                              void* d_out, int out_size, void* d_ws, size_t ws_size,
                              hipStream_t stream) {
    const float* x        = (const float*)d_in[0];
    const float* w_ih_l0  = (const float*)d_in[1];
    const float* w_hh_l0  = (const float*)d_in[2];
    const float* b_ih_l0  = (const float*)d_in[3];
    const float* b_hh_l0  = (const float*)d_in[4];
    const float* w_ih_l0r = (const float*)d_in[5];
    const float* w_hh_l0r = (const float*)d_in[6];
    const float* b_ih_l0r = (const float*)d_in[7];
    const float* b_hh_l0r = (const float*)d_in[8];
    const float* w_ih_l1  = (const float*)d_in[9];
    const float* w_hh_l1  = (const float*)d_in[10];
    const float* b_ih_l1  = (const float*)d_in[11];
    const float* b_hh_l1  = (const float*)d_in[12];
    const float* w_ih_l1r = (const float*)d_in[13];
    const float* w_hh_l1r = (const float*)d_in[14];
    const float* b_ih_l1r = (const float*)d_in[15];
    const float* b_hh_l1r = (const float*)d_in[16];
    const float* w_fc     = (const float*)d_in[17];
    const float* b_fc     = (const float*)d_in[18];

    float* ws    = (float*)d_ws;
    float* pre_f = ws;                       // 16,777,216 floats
    float* pre_b = ws + 16777216;            // 16,777,216 floats
    float* out0  = ws + 2 * 16777216;        // 8,388,608 floats
    float* out1  = out0 + 8388608;           // 8,388,608 floats

    // A hi/lo aliases (lifetimes proven R6/R7):
    short* xhi  = (short*)out0;
    short* xlo  = xhi + 2097152;
    short* a1hi = (short*)out1;
    short* a1lo = a1hi + 8388608;

    dim3 gg(256, 4);  // M/128 x 512/128

    // Layer 0
    convert_hilo<<<2048, 256, 0, stream>>>((const float4*)x, (s16x4*)xhi, (s16x4*)xlo, 524288);
    gemm_mfma2<64><<<gg, 256, 0, stream>>>(xhi, xlo, w_ih_l0,  b_ih_l0,  b_hh_l0,  pre_f);
    gemm_mfma2<64><<<gg, 256, 0, stream>>>(xhi, xlo, w_ih_l0r, b_ih_l0r, b_hh_l0r, pre_b);
    lstm_scan_v13<<<128, 256, 0, stream>>>(pre_f, pre_b, w_hh_l0, w_hh_l0r, out0);

    // Layer 1
    convert_hilo<<<2048, 256, 0, stream>>>((const float4*)out0, (s16x4*)a1hi, (s16x4*)a1lo, 2097152);
    gemm_mfma2<256><<<gg, 256, 0, stream>>>(a1hi, a1lo, w_ih_l1,  b_ih_l1,  b_hh_l1,  pre_f);
    gemm_mfma2<256><<<gg, 256, 0, stream>>>(a1hi, a1lo, w_ih_l1r, b_ih_l1r, b_hh_l1r, pre_b);
    lstm_scan_v13<<<128, 256, 0, stream>>>(pre_f, pre_b, w_hh_l1, w_hh_l1r, out1);

    // FC
    fc_v2<<<512, 256, 0, stream>>>(out1, w_fc, b_fc, (float*)d_out);
}

// Round 17
// 694.657 us; speedup vs baseline: 1.1621x; 1.1621x over previous
//
#include <hip/hip_runtime.h>

#define TT 512   // sequence length
#define BB 64    // batch
#define HH 128   // hidden
#define G4 512   // 4*H
#define PF 4     // prefetch ring depth == out-chunk size (even, divides TT)

typedef short bf16x8 __attribute__((ext_vector_type(8)));
typedef short s16x4  __attribute__((ext_vector_type(4)));
typedef float f32x4  __attribute__((ext_vector_type(4)));
typedef _Float16 f16x8v __attribute__((ext_vector_type(8)));

__device__ __forceinline__ unsigned short f2bf(float x) {
    unsigned u = __float_as_uint(x);
    u += 0x7fff + ((u >> 16) & 1);           // RNE
    return (unsigned short)(u >> 16);
}
__device__ __forceinline__ float bf2f(unsigned short h) {
    return __uint_as_float(((unsigned)h) << 16);
}

// barrier that waits ONLY on LDS (lgkmcnt) -- leaves global loads/stores in
// flight across the barrier (T4 counted-vmcnt philosophy). Single asm with
// memory clobber: no LDS op can be reordered across it.
__device__ __forceinline__ void barrier_lds_only() {
    asm volatile("s_waitcnt lgkmcnt(0)\n\ts_barrier" ::: "memory");
}

// ---------------- fp32 -> bf16 hi/lo split (memory-bound) ----------------
__global__ __launch_bounds__(256) void convert_hilo(
    const float4* __restrict__ src, s16x4* __restrict__ hi,
    s16x4* __restrict__ lo, int n4)
{
    for (int i = blockIdx.x * 256 + threadIdx.x; i < n4; i += gridDim.x * 256) {
        float4 f = src[i];
        float fa[4] = {f.x, f.y, f.z, f.w};
        s16x4 h, l;
        #pragma unroll
        for (int e = 0; e < 4; ++e) {
            unsigned short hh = f2bf(fa[e]);
            h[e] = (short)hh;
            l[e] = (short)f2bf(fa[e] - bf2f(hh));
        }
        hi[i] = h;
        lo[i] = l;
    }
}

// ---------------- MFMA pre-GEMM v3: A and W both pre-split bf16 ----------------
// Numerically proven by R9/R10 bit-equivalence (mfma3 vs mfma2 identical output).
// Staging is pure b128 load->store; 3-term hi/lo product. Tile 128x128, KC=32.
template<int K>
__global__ __launch_bounds__(256) void gemm_mfma3(
    const short* __restrict__ Ahi, const short* __restrict__ Alo,
    const short* __restrict__ Whi, const short* __restrict__ Wlo,
    const float* __restrict__ b0, const float* __restrict__ b1,
    float* __restrict__ C)
{
    constexpr int NC  = K / 32;
    constexpr int LDA = 40;                  // shorts per staged row (32 + 8 pad)
    __shared__ short Ahi_s[128 * LDA], Alo_s[128 * LDA];
    __shared__ short Whi_s[128 * LDA], Wlo_s[128 * LDA];

    const int bm  = blockIdx.x * 128;
    const int bn  = blockIdx.y * 128;
    const int tid = threadIdx.x;
    const int wv  = tid >> 6;
    const int l   = tid & 63;
    const int jl  = l & 15;
    const int rg  = l >> 4;
    const int wr  = wv >> 1;
    const int wc  = wv & 1;

    const int sr = tid >> 1;
    const int sc = (tid & 1) * 16;

    const short* Aph = Ahi + (size_t)(bm + sr) * K + sc;
    const short* Apl = Alo + (size_t)(bm + sr) * K + sc;
    const short* Wph = Whi + (size_t)(bn + sr) * K + sc;
    const short* Wpl = Wlo + (size_t)(bn + sr) * K + sc;

    f32x4 acc[4][4];
    #pragma unroll
    for (int i = 0; i < 4; ++i)
        #pragma unroll
        for (int j = 0; j < 4; ++j)
            acc[i][j] = (f32x4){0.f, 0.f, 0.f, 0.f};

    bf16x8 pah[2], pal[2], pwh[2], pwl[2];
    pah[0] = *(const bf16x8*)(Aph);     pah[1] = *(const bf16x8*)(Aph + 8);
    pal[0] = *(const bf16x8*)(Apl);     pal[1] = *(const bf16x8*)(Apl + 8);
    pwh[0] = *(const bf16x8*)(Wph);     pwh[1] = *(const bf16x8*)(Wph + 8);
    pwl[0] = *(const bf16x8*)(Wpl);     pwl[1] = *(const bf16x8*)(Wpl + 8);

    #pragma unroll 1
    for (int c = 0; c < NC; ++c) {
        __syncthreads();
        {
            int off = sr * LDA + sc;
            *(bf16x8*)&Ahi_s[off]     = pah[0];
            *(bf16x8*)&Ahi_s[off + 8] = pah[1];
            *(bf16x8*)&Alo_s[off]     = pal[0];
            *(bf16x8*)&Alo_s[off + 8] = pal[1];
            *(bf16x8*)&Whi_s[off]     = pwh[0];
            *(bf16x8*)&Whi_s[off + 8] = pwh[1];
            *(bf16x8*)&Wlo_s[off]     = pwl[0];
            *(bf16x8*)&Wlo_s[off + 8] = pwl[1];
        }
        __syncthreads();
        if (c + 1 < NC) {
            pah[0] = *(const bf16x8*)(Aph + (c + 1) * 32);
            pah[1] = *(const bf16x8*)(Aph + (c + 1) * 32 + 8);
            pal[0] = *(const bf16x8*)(Apl + (c + 1) * 32);
            pal[1] = *(const bf16x8*)(Apl + (c + 1) * 32 + 8);
            pwh[0] = *(const bf16x8*)(Wph + (c + 1) * 32);
            pwh[1] = *(const bf16x8*)(Wph + (c + 1) * 32 + 8);
            pwl[0] = *(const bf16x8*)(Wpl + (c + 1) * 32);
            pwl[1] = *(const bf16x8*)(Wpl + (c + 1) * 32 + 8);
        }
        bf16x8 ah[4], al[4], wh[4], wl[4];
        #pragma unroll
        for (int t = 0; t < 4; ++t) {
            int ra = (wr * 64 + t * 16 + jl) * LDA + rg * 8;
            ah[t] = *(const bf16x8*)&Ahi_s[ra];
            al[t] = *(const bf16x8*)&Alo_s[ra];
            int rw = (wc * 64 + t * 16 + jl) * LDA + rg * 8;
            wh[t] = *(const bf16x8*)&Whi_s[rw];
            wl[t] = *(const bf16x8*)&Wlo_s[rw];
        }
        #pragma unroll
        for (int tm = 0; tm < 4; ++tm)
            #pragma unroll
            for (int tn = 0; tn < 4; ++tn) {
                acc[tm][tn] = __builtin_amdgcn_mfma_f32_16x16x32_bf16(ah[tm], wh[tn], acc[tm][tn], 0, 0, 0);
                acc[tm][tn] = __builtin_amdgcn_mfma_f32_16x16x32_bf16(ah[tm], wl[tn], acc[tm][tn], 0, 0, 0);
                acc[tm][tn] = __builtin_amdgcn_mfma_f32_16x16x32_bf16(al[tm], wh[tn], acc[tm][tn], 0, 0, 0);
            }
    }

    // epilogue: C layout col=lane&15 (n), row=(lane>>4)*4+r (m)
    #pragma unroll
    for (int tn = 0; tn < 4; ++tn) {
        int n = bn + wc * 64 + tn * 16 + jl;
        float bias = b0[n] + b1[n];
        #pragma unroll
        for (int tm = 0; tm < 4; ++tm) {
            int m = bm + wr * 64 + tm * 16 + rg * 4;
            #pragma unroll
            for (int r = 0; r < 4; ++r)
                C[(size_t)(m + r) * G4 + n] = acc[tm][tn][r] + bias;
        }
    }
}

// ---------------- LSTM scan v14: v12 + lgkm-only barrier ----------------
// 128 blocks = 2dir x 64batch (1 seq each), 512 thr (8 waves) -- v12's proven
// shape (R15: 257 us, MfmaUtil 21%). ONLY change: the per-step barrier waits
// lgkmcnt(0) only, NOT vmcnt(0) -- the PF-ring refill loads and oring global
// stores stay in flight across barriers (drain was nullifying the ring's
// 4-step latency window). All arithmetic identical to v12 (absmax 9.77e-4).
__global__ __launch_bounds__(512) void lstm_scan_v14(
    const float* __restrict__ pre_f, const float* __restrict__ pre_b,
    const float* __restrict__ whh_f, const float* __restrict__ whh_b,
    float* __restrict__ out)
{
    const int dir = blockIdx.x >> 6;
    const int b   = blockIdx.x & 63;
    const float* __restrict__ pre  = dir ? pre_b : pre_f;
    const float* __restrict__ w_hh = dir ? whh_b : whh_f;

    const int tid = threadIdx.x;
    const int w   = tid >> 6;        // wave 0..7
    const int l   = tid & 63;
    const int jl  = l & 15;
    const int rg  = l >> 4;          // 0..3

    __shared__ _Float16 h_lds[2][HH];
    __shared__ float oring[2][PF][HH];

    // B fragments: gate rows (cc*128 + w*16 + jl), k = kc*32 + rg*8 + e
    f16x8v bw[4][4];
    #pragma unroll
    for (int cc = 0; cc < 4; ++cc) {
        const float* wr_ = w_hh + (size_t)(cc * HH + w * 16 + jl) * HH + rg * 8;
        #pragma unroll
        for (int kc = 0; kc < 4; ++kc) {
            const float* p_ = wr_ + kc * 32;
            f16x8v f;
            #pragma unroll
            for (int e = 0; e < 8; ++e) f[e] = (_Float16)p_[e];
            bw[cc][kc] = f;
        }
    }

    if (tid < 2 * HH) ((_Float16*)h_lds)[tid] = (_Float16)0.f;

    // pre ring: lane pattern repeats every 16 lanes; only lanes 0-15 consumed
    const size_t base = (size_t)b * TT * G4 + w * 16 + jl;
    float pf[PF][4];
    #pragma unroll
    for (int u = 0; u < PF; ++u) {
        int tau = dir ? (TT - 1 - u) : u;
        #pragma unroll
        for (int cc = 0; cc < 4; ++cc)
            pf[u][cc] = pre[base + (size_t)tau * G4 + cc * HH];
    }

    float c = 0.f;
    const float ASIG = -1.4426950408889634f;  // -log2(e)
    const float ATAN =  2.8853900817779268f;  // 2*log2(e)

    const int s_loc = tid >> 7;      // 0..3 (PF=4)
    const int c128  = tid & 127;

    __syncthreads();

    for (int s0 = 0; s0 < TT; s0 += PF) {
        const int p = (s0 >> 2) & 1;          // oring parity for this chunk
        #pragma unroll
        for (int u = 0; u < PF; ++u) {
            const int s = s0 + u;
            const int cur = u & 1;            // parity(s) == parity(u)

            // A fragments: wave-uniform per rg-group; rows 1-15 replicate h
            f16x8v a[4];
            #pragma unroll
            for (int kc = 0; kc < 4; ++kc)
                a[kc] = *(const f16x8v*)&h_lds[cur][kc * 32 + rg * 8];

            // C init from pre (row rg*4 real; other rows junk), pv BEFORE refill
            f32x4 acc[4];
            #pragma unroll
            for (int cc = 0; cc < 4; ++cc)
                acc[cc] = (f32x4){pf[u][cc], 0.f, 0.f, 0.f};

            // ring refill (clamped; loads now survive across barriers ->
            // full 4-step window to hide HBM latency)
            {
                int sn = s + PF;
                int taun = dir ? (TT - 1 - sn) : sn;
                taun = taun < 0 ? 0 : (taun > TT - 1 ? TT - 1 : taun);
                #pragma unroll
                for (int cc = 0; cc < 4; ++cc)
                    pf[u][cc] = pre[base + (size_t)taun * G4 + cc * HH];
            }

            // 16 MFMA: G[gates of this wave] += Whh-chunk . h-chunk
            #pragma unroll
            for (int cc = 0; cc < 4; ++cc)
                #pragma unroll
                for (int kc = 0; kc < 4; ++kc)
                    acc[cc] = __builtin_amdgcn_mfma_f32_16x16x32_f16(
                        a[kc], bw[cc][kc], acc[cc], 0, 0, 0);

            // tail: lanes 0-15 hold cell (w*16+l): i,f,g,o in acc[cc][0]
            if (l < 16) {
                float gi = acc[0][0], gf = acc[1][0], gg = acc[2][0], go = acc[3][0];
                float ei = __builtin_amdgcn_exp2f(ASIG * gi);
                float si = __builtin_amdgcn_rcpf(1.f + ei);
                float ef = __builtin_amdgcn_exp2f(ASIG * gf);
                float sf = __builtin_amdgcn_rcpf(1.f + ef);
                float eg = __builtin_amdgcn_exp2f(ATAN * gg);
                float tg = 1.f - 2.f * __builtin_amdgcn_rcpf(1.f + eg);
                float eo = __builtin_amdgcn_exp2f(ASIG * go);
                float so = __builtin_amdgcn_rcpf(1.f + eo);
                c = fmaf(sf, c, si * tg);
                float e2 = __builtin_amdgcn_exp2f(ATAN * c);
                float h  = so * (1.f - 2.f * __builtin_amdgcn_rcpf(1.f + e2));
                int j = w * 16 + l;
                h_lds[cur ^ 1][j] = (_Float16)h;
                oring[p][u][j] = h;
            }
            barrier_lds_only();
        }

        // coalesced burst-write of the finished chunk; store stays in flight
        // (WAR on oring[p] is 4 barriers away; the LDS read completes first)
        {
            int sb = s0 + s_loc;
            int tau = dir ? (TT - 1 - sb) : sb;
            out[((size_t)b * TT + tau) * (2 * HH) + dir * HH + c128] =
                oring[p][s_loc][c128];
        }
    }
}

// ---------------- FC v2 (proven R7) ----------------
__global__ __launch_bounds__(256) void fc_v2(
    const float* __restrict__ h2, const float* __restrict__ w_fc,
    const float* __restrict__ b_fc, float* __restrict__ out)
{
    __shared__ float4 wsT[64][64];          // [k4][n]
    const int tid = threadIdx.x;
    const int bm  = blockIdx.x * 64;
    const int n   = tid & 63;
    const int mg  = tid >> 6;

    #pragma unroll
    for (int qq = 0; qq < 16; ++qq) {
        int id = qq * 256 + tid;
        int nn = id >> 6, k4 = id & 63;
        wsT[k4][nn] = *(const float4*)&w_fc[(size_t)nn * 256 + k4 * 4];
    }
    __syncthreads();

    const float bias = b_fc[n];
    const float* hrow = h2 + (size_t)(bm + mg * 16) * 256;

    float acc[16];
    #pragma unroll
    for (int mi = 0; mi < 16; ++mi) acc[mi] = 0.f;

    #pragma unroll 2
    for (int k4 = 0; k4 < 64; ++k4) {
        float4 w4 = wsT[k4][n];
        #pragma unroll
        for (int mi = 0; mi < 16; ++mi) {
            float4 h4 = *(const float4*)(hrow + (size_t)mi * 256 + k4 * 4);
            acc[mi] = fmaf(h4.x, w4.x, acc[mi]);
            acc[mi] = fmaf(h4.y, w4.y, acc[mi]);
            acc[mi] = fmaf(h4.z, w4.z, acc[mi]);
            acc[mi] = fmaf(h4.w, w4.w, acc[mi]);
        }
    }
    #pragma unroll
    for (int mi = 0; mi < 16; ++mi)
        out[(size_t)(bm + mg * 16 + mi) * 64 + n] = acc[mi] + bias;
}

extern "C" void kernel_launch(void* const* d_in, const int* in_sizes, int n_in,
                              void* d_out, int out_size, void* d_ws, size_t ws_size,
                              hipStream_t stream) {
    const float* x        = (const float*)d_in[0];
    const float* w_ih_l0  = (const float*)d_in[1];
    const float* w_hh_l0  = (const float*)d_in[2];
    const float* b_ih_l0  = (const float*)d_in[3];
    const float* b_hh_l0  = (const float*)d_in[4];
    const float* w_ih_l0r = (const float*)d_in[5];
    const float* w_hh_l0r = (const float*)d_in[6];
    const float* b_ih_l0r = (const float*)d_in[7];
    const float* b_hh_l0r = (const float*)d_in[8];
    const float* w_ih_l1  = (const float*)d_in[9];
    const float* w_hh_l1  = (const float*)d_in[10];
    const float* b_ih_l1  = (const float*)d_in[11];
    const float* b_hh_l1  = (const float*)d_in[12];
    const float* w_ih_l1r = (const float*)d_in[13];
    const float* w_hh_l1r = (const float*)d_in[14];
    const float* b_ih_l1r = (const float*)d_in[15];
    const float* b_hh_l1r = (const float*)d_in[16];
    const float* w_fc     = (const float*)d_in[17];
    const float* b_fc     = (const float*)d_in[18];

    float* ws    = (float*)d_ws;
    float* pre_f = ws;                       // 16,777,216 floats
    float* pre_b = ws + 16777216;            // 16,777,216 floats
    float* out0  = ws + 2 * 16777216;        // 8,388,608 floats
    float* out1  = out0 + 8388608;           // 8,388,608 floats

    // A hi/lo aliases (lifetimes proven R6/R7):
    short* xhi  = (short*)out0;
    short* xlo  = xhi + 2097152;
    short* a1hi = (short*)out1;
    short* a1lo = a1hi + 8388608;

    // W hi/lo scratch aliased into d_out (1.31 MB of 8.4 MB; fully overwritten
    // by fc_v2 at the end). Numerics proven by R9/R10 bit-equivalence.
    short* wsp    = (short*)d_out;
    short* w0f_hi = wsp;              short* w0f_lo = wsp + 32768;
    short* w0r_hi = wsp + 65536;      short* w0r_lo = wsp + 98304;
    short* w1f_hi = wsp + 131072;     short* w1f_lo = wsp + 262144;
    short* w1r_hi = wsp + 393216;     short* w1r_lo = wsp + 524288;

    dim3 gg(256, 4);  // M/128 x 512/128

    // weight splits (inputs const -> all up front)
    convert_hilo<<<32,  256, 0, stream>>>((const float4*)w_ih_l0,  (s16x4*)w0f_hi, (s16x4*)w0f_lo, 8192);
    convert_hilo<<<32,  256, 0, stream>>>((const float4*)w_ih_l0r, (s16x4*)w0r_hi, (s16x4*)w0r_lo, 8192);
    convert_hilo<<<128, 256, 0, stream>>>((const float4*)w_ih_l1,  (s16x4*)w1f_hi, (s16x4*)w1f_lo, 32768);
    convert_hilo<<<128, 256, 0, stream>>>((const float4*)w_ih_l1r, (s16x4*)w1r_hi, (s16x4*)w1r_lo, 32768);

    // Layer 0
    convert_hilo<<<2048, 256, 0, stream>>>((const float4*)x, (s16x4*)xhi, (s16x4*)xlo, 524288);
    gemm_mfma3<64><<<gg, 256, 0, stream>>>(xhi, xlo, w0f_hi, w0f_lo, b_ih_l0,  b_hh_l0,  pre_f);
    gemm_mfma3<64><<<gg, 256, 0, stream>>>(xhi, xlo, w0r_hi, w0r_lo, b_ih_l0r, b_hh_l0r, pre_b);
    lstm_scan_v14<<<128, 512, 0, stream>>>(pre_f, pre_b, w_hh_l0, w_hh_l0r, out0);

    // Layer 1
    convert_hilo<<<2048, 256, 0, stream>>>((const float4*)out0, (s16x4*)a1hi, (s16x4*)a1lo, 2097152);
    gemm_mfma3<256><<<gg, 256, 0, stream>>>(a1hi, a1lo, w1f_hi, w1f_lo, b_ih_l1,  b_hh_l1,  pre_f);
    gemm_mfma3<256><<<gg, 256, 0, stream>>>(a1hi, a1lo, w1r_hi, w1r_lo, b_ih_l1r, b_hh_l1r, pre_b);
    lstm_scan_v14<<<128, 512, 0, stream>>>(pre_f, pre_b, w_hh_l1, w_hh_l1r, out1);

    // FC (overwrites the W-split scratch in d_out)
    fc_v2<<<512, 256, 0, stream>>>(out1, w_fc, b_fc, (float*)d_out);
}

// Round 18
// 661.448 us; speedup vs baseline: 1.2204x; 1.0502x over previous
//
#include <hip/hip_runtime.h>

#define TT 512   // sequence length
#define BB 64    // batch
#define HH 128   // hidden
#define G4 512   // 4*H
#define PF 4     // prefetch ring depth == out-chunk size (even, divides TT)

typedef float f32x4  __attribute__((ext_vector_type(4)));
typedef _Float16 f16x4v __attribute__((ext_vector_type(4)));
typedef _Float16 f16x8v __attribute__((ext_vector_type(8)));

// barrier that waits ONLY on LDS (lgkmcnt) -- leaves global ops in flight.
__device__ __forceinline__ void barrier_lds_only() {
    asm volatile("s_waitcnt lgkmcnt(0)\n\ts_barrier" ::: "memory");
}

// ---------------- fp32 -> fp16 convert (memory-bound) ----------------
__global__ __launch_bounds__(256) void convert_f16(
    const float4* __restrict__ src, f16x4v* __restrict__ dst, int n4)
{
    for (int i = blockIdx.x * 256 + threadIdx.x; i < n4; i += gridDim.x * 256) {
        float4 f = src[i];
        f16x4v h;
        h[0] = (_Float16)f.x; h[1] = (_Float16)f.y;
        h[2] = (_Float16)f.z; h[3] = (_Float16)f.w;
        dst[i] = h;
    }
}

// ---------------- f16 pre-GEMM: C[m,n] = sum_k A[m,k]W[n,k] + b0[n]+b1[n] ----
// A,W pre-converted f16 (precision matches the scan's f16 path; threshold
// margin ~6x). Single MFMA per tile-pair (3x fewer than hi/lo). Tile 128x128,
// KC=32, 4 waves; staging is pure b128 load->store. LDS 20KB -> high occupancy.
template<int K>
__global__ __launch_bounds__(256) void gemm_f16(
    const _Float16* __restrict__ Af, const _Float16* __restrict__ Wf,
    const float* __restrict__ b0, const float* __restrict__ b1,
    float* __restrict__ C)
{
    constexpr int NC  = K / 32;
    constexpr int LDA = 40;                  // f16 per staged row (32 + 8 pad)
    __shared__ _Float16 As[128 * LDA];
    __shared__ _Float16 Ws[128 * LDA];

    const int bm  = blockIdx.x * 128;
    const int bn  = blockIdx.y * 128;
    const int tid = threadIdx.x;
    const int wv  = tid >> 6;
    const int l   = tid & 63;
    const int jl  = l & 15;
    const int rg  = l >> 4;
    const int wr  = wv >> 1;
    const int wc  = wv & 1;

    const int sr = tid >> 1;         // staging row 0..127
    const int sc = (tid & 1) * 16;   // staging col base

    const _Float16* Ap = Af + (size_t)(bm + sr) * K + sc;
    const _Float16* Wp = Wf + (size_t)(bn + sr) * K + sc;

    f32x4 acc[4][4];
    #pragma unroll
    for (int i = 0; i < 4; ++i)
        #pragma unroll
        for (int j = 0; j < 4; ++j)
            acc[i][j] = (f32x4){0.f, 0.f, 0.f, 0.f};

    f16x8v pa[2], pw[2];
    pa[0] = *(const f16x8v*)(Ap);     pa[1] = *(const f16x8v*)(Ap + 8);
    pw[0] = *(const f16x8v*)(Wp);     pw[1] = *(const f16x8v*)(Wp + 8);

    #pragma unroll 1
    for (int c = 0; c < NC; ++c) {
        __syncthreads();
        {
            int off = sr * LDA + sc;
            *(f16x8v*)&As[off]     = pa[0];
            *(f16x8v*)&As[off + 8] = pa[1];
            *(f16x8v*)&Ws[off]     = pw[0];
            *(f16x8v*)&Ws[off + 8] = pw[1];
        }
        __syncthreads();
        if (c + 1 < NC) {
            pa[0] = *(const f16x8v*)(Ap + (c + 1) * 32);
            pa[1] = *(const f16x8v*)(Ap + (c + 1) * 32 + 8);
            pw[0] = *(const f16x8v*)(Wp + (c + 1) * 32);
            pw[1] = *(const f16x8v*)(Wp + (c + 1) * 32 + 8);
        }
        f16x8v ah[4], wh[4];
        #pragma unroll
        for (int t = 0; t < 4; ++t) {
            ah[t] = *(const f16x8v*)&As[(wr * 64 + t * 16 + jl) * LDA + rg * 8];
            wh[t] = *(const f16x8v*)&Ws[(wc * 64 + t * 16 + jl) * LDA + rg * 8];
        }
        #pragma unroll
        for (int tm = 0; tm < 4; ++tm)
            #pragma unroll
            for (int tn = 0; tn < 4; ++tn)
                acc[tm][tn] = __builtin_amdgcn_mfma_f32_16x16x32_f16(
                    ah[tm], wh[tn], acc[tm][tn], 0, 0, 0);
    }

    // epilogue: C layout col=lane&15 (n), row=(lane>>4)*4+r (m)
    #pragma unroll
    for (int tn = 0; tn < 4; ++tn) {
        int n = bn + wc * 64 + tn * 16 + jl;
        float bias = b0[n] + b1[n];
        #pragma unroll
        for (int tm = 0; tm < 4; ++tm) {
            int m = bm + wr * 64 + tm * 16 + rg * 4;
            #pragma unroll
            for (int r = 0; r < 4; ++r)
                C[(size_t)(m + r) * G4 + n] = acc[tm][tn][r] + bias;
        }
    }
}

// ---------------- LSTM scan v14 (R17-proven: 260 us, absmax 9.77e-4) ----------
__global__ __launch_bounds__(512) void lstm_scan_v14(
    const float* __restrict__ pre_f, const float* __restrict__ pre_b,
    const float* __restrict__ whh_f, const float* __restrict__ whh_b,
    float* __restrict__ out)
{
    const int dir = blockIdx.x >> 6;
    const int b   = blockIdx.x & 63;
    const float* __restrict__ pre  = dir ? pre_b : pre_f;
    const float* __restrict__ w_hh = dir ? whh_b : whh_f;

    const int tid = threadIdx.x;
    const int w   = tid >> 6;        // wave 0..7
    const int l   = tid & 63;
    const int jl  = l & 15;
    const int rg  = l >> 4;          // 0..3

    __shared__ _Float16 h_lds[2][HH];
    __shared__ float oring[2][PF][HH];

    // B fragments: gate rows (cc*128 + w*16 + jl), k = kc*32 + rg*8 + e
    f16x8v bw[4][4];
    #pragma unroll
    for (int cc = 0; cc < 4; ++cc) {
        const float* wr_ = w_hh + (size_t)(cc * HH + w * 16 + jl) * HH + rg * 8;
        #pragma unroll
        for (int kc = 0; kc < 4; ++kc) {
            const float* p_ = wr_ + kc * 32;
            f16x8v f;
            #pragma unroll
            for (int e = 0; e < 8; ++e) f[e] = (_Float16)p_[e];
            bw[cc][kc] = f;
        }
    }

    if (tid < 2 * HH) ((_Float16*)h_lds)[tid] = (_Float16)0.f;

    // pre ring: lane pattern repeats every 16 lanes; only lanes 0-15 consumed
    const size_t base = (size_t)b * TT * G4 + w * 16 + jl;
    float pf[PF][4];
    #pragma unroll
    for (int u = 0; u < PF; ++u) {
        int tau = dir ? (TT - 1 - u) : u;
        #pragma unroll
        for (int cc = 0; cc < 4; ++cc)
            pf[u][cc] = pre[base + (size_t)tau * G4 + cc * HH];
    }

    float c = 0.f;
    const float ASIG = -1.4426950408889634f;  // -log2(e)
    const float ATAN =  2.8853900817779268f;  // 2*log2(e)

    const int s_loc = tid >> 7;      // 0..3 (PF=4)
    const int c128  = tid & 127;

    __syncthreads();

    for (int s0 = 0; s0 < TT; s0 += PF) {
        const int p = (s0 >> 2) & 1;          // oring parity for this chunk
        #pragma unroll
        for (int u = 0; u < PF; ++u) {
            const int s = s0 + u;
            const int cur = u & 1;            // parity(s) == parity(u)

            // A fragments: wave-uniform per rg-group; rows 1-15 junk (unread)
            f16x8v a[4];
            #pragma unroll
            for (int kc = 0; kc < 4; ++kc)
                a[kc] = *(const f16x8v*)&h_lds[cur][kc * 32 + rg * 8];

            // C init from pre (row 0 real), pv captured BEFORE refill
            f32x4 acc[4];
            #pragma unroll
            for (int cc = 0; cc < 4; ++cc)
                acc[cc] = (f32x4){pf[u][cc], 0.f, 0.f, 0.f};

            // ring refill (clamped; loads survive across lgkm-only barriers)
            {
                int sn = s + PF;
                int taun = dir ? (TT - 1 - sn) : sn;
                taun = taun < 0 ? 0 : (taun > TT - 1 ? TT - 1 : taun);
                #pragma unroll
                for (int cc = 0; cc < 4; ++cc)
                    pf[u][cc] = pre[base + (size_t)taun * G4 + cc * HH];
            }

            // 16 MFMA: G[gates of this wave] += Whh-chunk . h-chunk
            #pragma unroll
            for (int cc = 0; cc < 4; ++cc)
                #pragma unroll
                for (int kc = 0; kc < 4; ++kc)
                    acc[cc] = __builtin_amdgcn_mfma_f32_16x16x32_f16(
                        a[kc], bw[cc][kc], acc[cc], 0, 0, 0);

            // tail: lanes 0-15 hold cell (w*16+l): i,f,g,o in acc[cc][0]
            if (l < 16) {
                float gi = acc[0][0], gf = acc[1][0], gg = acc[2][0], go = acc[3][0];
                float ei = __builtin_amdgcn_exp2f(ASIG * gi);
                float si = __builtin_amdgcn_rcpf(1.f + ei);
                float ef = __builtin_amdgcn_exp2f(ASIG * gf);
                float sf = __builtin_amdgcn_rcpf(1.f + ef);
                float eg = __builtin_amdgcn_exp2f(ATAN * gg);
                float tg = 1.f - 2.f * __builtin_amdgcn_rcpf(1.f + eg);
                float eo = __builtin_amdgcn_exp2f(ASIG * go);
                float so = __builtin_amdgcn_rcpf(1.f + eo);
                c = fmaf(sf, c, si * tg);
                float e2 = __builtin_amdgcn_exp2f(ATAN * c);
                float h  = so * (1.f - 2.f * __builtin_amdgcn_rcpf(1.f + e2));
                int j = w * 16 + l;
                h_lds[cur ^ 1][j] = (_Float16)h;
                oring[p][u][j] = h;
            }
            barrier_lds_only();
        }

        // coalesced burst-write of the finished chunk
        {
            int sb = s0 + s_loc;
            int tau = dir ? (TT - 1 - sb) : sb;
            out[((size_t)b * TT + tau) * (2 * HH) + dir * HH + c128] =
                oring[p][s_loc][c128];
        }
    }
}

// ---------------- FC v2 (proven R7) ----------------
__global__ __launch_bounds__(256) void fc_v2(
    const float* __restrict__ h2, const float* __restrict__ w_fc,
    const float* __restrict__ b_fc, float* __restrict__ out)
{
    __shared__ float4 wsT[64][64];          // [k4][n]
    const int tid = threadIdx.x;
    const int bm  = blockIdx.x * 64;
    const int n   = tid & 63;
    const int mg  = tid >> 6;

    #pragma unroll
    for (int qq = 0; qq < 16; ++qq) {
        int id = qq * 256 + tid;
        int nn = id >> 6, k4 = id & 63;
        wsT[k4][nn] = *(const float4*)&w_fc[(size_t)nn * 256 + k4 * 4];
    }
    __syncthreads();

    const float bias = b_fc[n];
    const float* hrow = h2 + (size_t)(bm + mg * 16) * 256;

    float acc[16];
    #pragma unroll
    for (int mi = 0; mi < 16; ++mi) acc[mi] = 0.f;

    #pragma unroll 2
    for (int k4 = 0; k4 < 64; ++k4) {
        float4 w4 = wsT[k4][n];
        #pragma unroll
        for (int mi = 0; mi < 16; ++mi) {
            float4 h4 = *(const float4*)(hrow + (size_t)mi * 256 + k4 * 4);
            acc[mi] = fmaf(h4.x, w4.x, acc[mi]);
            acc[mi] = fmaf(h4.y, w4.y, acc[mi]);
            acc[mi] = fmaf(h4.z, w4.z, acc[mi]);
            acc[mi] = fmaf(h4.w, w4.w, acc[mi]);
        }
    }
    #pragma unroll
    for (int mi = 0; mi < 16; ++mi)
        out[(size_t)(bm + mg * 16 + mi) * 64 + n] = acc[mi] + bias;
}

extern "C" void kernel_launch(void* const* d_in, const int* in_sizes, int n_in,
                              void* d_out, int out_size, void* d_ws, size_t ws_size,
                              hipStream_t stream) {
    const float* x        = (const float*)d_in[0];
    const float* w_ih_l0  = (const float*)d_in[1];
    const float* w_hh_l0  = (const float*)d_in[2];
    const float* b_ih_l0  = (const float*)d_in[3];
    const float* b_hh_l0  = (const float*)d_in[4];
    const float* w_ih_l0r = (const float*)d_in[5];
    const float* w_hh_l0r = (const float*)d_in[6];
    const float* b_ih_l0r = (const float*)d_in[7];
    const float* b_hh_l0r = (const float*)d_in[8];
    const float* w_ih_l1  = (const float*)d_in[9];
    const float* w_hh_l1  = (const float*)d_in[10];
    const float* b_ih_l1  = (const float*)d_in[11];
    const float* b_hh_l1  = (const float*)d_in[12];
    const float* w_ih_l1r = (const float*)d_in[13];
    const float* w_hh_l1r = (const float*)d_in[14];
    const float* b_ih_l1r = (const float*)d_in[15];
    const float* b_hh_l1r = (const float*)d_in[16];
    const float* w_fc     = (const float*)d_in[17];
    const float* b_fc     = (const float*)d_in[18];

    float* ws    = (float*)d_ws;
    float* pre_f = ws;                       // 16,777,216 floats
    float* pre_b = ws + 16777216;            // 16,777,216 floats
    float* out0  = ws + 2 * 16777216;        // 8,388,608 floats
    float* out1  = out0 + 8388608;           // 8,388,608 floats

    // f16 activation scratch aliased (lifetime pattern proven R6-R17):
    //  x_f16 in out0 region (consumed by gemm l0 before scan l0 writes out0)
    //  a1_f16 in out1 region (consumed by gemm l1 before scan l1 writes out1)
    _Float16* xf16  = (_Float16*)out0;       // 2,097,152 f16 (4 MB)
    _Float16* a1f16 = (_Float16*)out1;       // 8,388,608 f16 (16.8 MB)

    // W f16 scratch in d_out (655 KB of 8.4 MB; fully overwritten by fc_v2
    // at the end -- pattern proven R16/R17)
    _Float16* wsp  = (_Float16*)d_out;
    _Float16* w0f  = wsp;                    // 32,768 f16
    _Float16* w0r  = wsp + 32768;
    _Float16* w1f  = wsp + 65536;            // 131,072 f16
    _Float16* w1r  = wsp + 196608;           // end 327,680

    dim3 gg(256, 4);  // M/128 x 512/128

    // weight converts (inputs const -> all up front)
    convert_f16<<<32,   256, 0, stream>>>((const float4*)w_ih_l0,  (f16x4v*)w0f, 8192);
    convert_f16<<<32,   256, 0, stream>>>((const float4*)w_ih_l0r, (f16x4v*)w0r, 8192);
    convert_f16<<<128,  256, 0, stream>>>((const float4*)w_ih_l1,  (f16x4v*)w1f, 32768);
    convert_f16<<<128,  256, 0, stream>>>((const float4*)w_ih_l1r, (f16x4v*)w1r, 32768);

    // Layer 0
    convert_f16<<<2048, 256, 0, stream>>>((const float4*)x, (f16x4v*)xf16, 524288);
    gemm_f16<64><<<gg, 256, 0, stream>>>(xf16, w0f, b_ih_l0,  b_hh_l0,  pre_f);
    gemm_f16<64><<<gg, 256, 0, stream>>>(xf16, w0r, b_ih_l0r, b_hh_l0r, pre_b);
    lstm_scan_v14<<<128, 512, 0, stream>>>(pre_f, pre_b, w_hh_l0, w_hh_l0r, out0);

    // Layer 1
    convert_f16<<<2048, 256, 0, stream>>>((const float4*)out0, (f16x4v*)a1f16, 2097152);
    gemm_f16<256><<<gg, 256, 0, stream>>>(a1f16, w1f, b_ih_l1,  b_hh_l1,  pre_f);
    gemm_f16<256><<<gg, 256, 0, stream>>>(a1f16, w1r, b_ih_l1r, b_hh_l1r, pre_b);
    lstm_scan_v14<<<128, 512, 0, stream>>>(pre_f, pre_b, w_hh_l1, w_hh_l1r, out1);

    // FC (overwrites the W-f16 scratch in d_out)
    fc_v2<<<512, 256, 0, stream>>>(out1, w_fc, b_fc, (float*)d_out);
}

// Round 19
// 571.861 us; speedup vs baseline: 1.4116x; 1.1567x over previous
//
#include <hip/hip_runtime.h>

#define TT 512   // sequence length
#define BB 64    // batch
#define HH 128   // hidden
#define G4 512   // 4*H
#define PF 4     // prefetch ring depth (even, divides TT)

typedef float f32x4  __attribute__((ext_vector_type(4)));
typedef _Float16 f16x4v __attribute__((ext_vector_type(4)));
typedef _Float16 f16x8v __attribute__((ext_vector_type(8)));

// barrier that waits ONLY on LDS (lgkmcnt) -- global loads/stores stay in flight
__device__ __forceinline__ void barrier_lds_only() {
    asm volatile("s_waitcnt lgkmcnt(0)\n\ts_barrier" ::: "memory");
}

// ---------------- fp32 -> fp16 convert (memory-bound) ----------------
__global__ __launch_bounds__(256) void convert_f16(
    const float4* __restrict__ src, f16x4v* __restrict__ dst, int n4)
{
    for (int i = blockIdx.x * 256 + threadIdx.x; i < n4; i += gridDim.x * 256) {
        float4 f = src[i];
        f16x4v h;
        h[0] = (_Float16)f.x; h[1] = (_Float16)f.y;
        h[2] = (_Float16)f.z; h[3] = (_Float16)f.w;
        dst[i] = h;
    }
}

// ---------------- f16 pre-GEMM: pre[m,n] = sum_k A[m,k]W[n,k] + b0[n]+b1[n] ----
// A,W f16; OUTPUT f16 (R19: halves pre-store traffic; scan consumes f16).
// Tile 128x128, KC=32, 4 waves; staging pure b128 load->store.
template<int K>
__global__ __launch_bounds__(256) void gemm_f16(
    const _Float16* __restrict__ Af, const _Float16* __restrict__ Wf,
    const float* __restrict__ b0, const float* __restrict__ b1,
    _Float16* __restrict__ C)
{
    constexpr int NC  = K / 32;
    constexpr int LDA = 40;                  // f16 per staged row (32 + 8 pad)
    __shared__ _Float16 As[128 * LDA];
    __shared__ _Float16 Ws[128 * LDA];

    const int bm  = blockIdx.x * 128;
    const int bn  = blockIdx.y * 128;
    const int tid = threadIdx.x;
    const int wv  = tid >> 6;
    const int l   = tid & 63;
    const int jl  = l & 15;
    const int rg  = l >> 4;
    const int wr  = wv >> 1;
    const int wc  = wv & 1;

    const int sr = tid >> 1;
    const int sc = (tid & 1) * 16;

    const _Float16* Ap = Af + (size_t)(bm + sr) * K + sc;
    const _Float16* Wp = Wf + (size_t)(bn + sr) * K + sc;

    f32x4 acc[4][4];
    #pragma unroll
    for (int i = 0; i < 4; ++i)
        #pragma unroll
        for (int j = 0; j < 4; ++j)
            acc[i][j] = (f32x4){0.f, 0.f, 0.f, 0.f};

    f16x8v pa[2], pw[2];
    pa[0] = *(const f16x8v*)(Ap);     pa[1] = *(const f16x8v*)(Ap + 8);
    pw[0] = *(const f16x8v*)(Wp);     pw[1] = *(const f16x8v*)(Wp + 8);

    #pragma unroll 1
    for (int c = 0; c < NC; ++c) {
        __syncthreads();
        {
            int off = sr * LDA + sc;
            *(f16x8v*)&As[off]     = pa[0];
            *(f16x8v*)&As[off + 8] = pa[1];
            *(f16x8v*)&Ws[off]     = pw[0];
            *(f16x8v*)&Ws[off + 8] = pw[1];
        }
        __syncthreads();
        if (c + 1 < NC) {
            pa[0] = *(const f16x8v*)(Ap + (c + 1) * 32);
            pa[1] = *(const f16x8v*)(Ap + (c + 1) * 32 + 8);
            pw[0] = *(const f16x8v*)(Wp + (c + 1) * 32);
            pw[1] = *(const f16x8v*)(Wp + (c + 1) * 32 + 8);
        }
        f16x8v ah[4], wh[4];
        #pragma unroll
        for (int t = 0; t < 4; ++t) {
            ah[t] = *(const f16x8v*)&As[(wr * 64 + t * 16 + jl) * LDA + rg * 8];
            wh[t] = *(const f16x8v*)&Ws[(wc * 64 + t * 16 + jl) * LDA + rg * 8];
        }
        #pragma unroll
        for (int tm = 0; tm < 4; ++tm)
            #pragma unroll
            for (int tn = 0; tn < 4; ++tn)
                acc[tm][tn] = __builtin_amdgcn_mfma_f32_16x16x32_f16(
                    ah[tm], wh[tn], acc[tm][tn], 0, 0, 0);
    }

    // epilogue: C layout col=lane&15 (n), row=(lane>>4)*4+r (m); f16 stores
    #pragma unroll
    for (int tn = 0; tn < 4; ++tn) {
        int n = bn + wc * 64 + tn * 16 + jl;
        float bias = b0[n] + b1[n];
        #pragma unroll
        for (int tm = 0; tm < 4; ++tm) {
            int m = bm + wr * 64 + tm * 16 + rg * 4;
            #pragma unroll
            for (int r = 0; r < 4; ++r)
                C[(size_t)(m + r) * G4 + n] = (_Float16)(acc[tm][tn][r] + bias);
        }
    }
}

// ---------------- LSTM scan v15: v14 + f16 pre in / f16 h out ----------------
// 128 blocks = 2dir x 64batch, 512 thr (8 waves). Identical compute to v14
// (R17-proven 260 us). Changes: pre read as f16 (convert per element), h
// stored DIRECTLY to f16 out (scattered 2B stores fly across the lgkm-only
// barrier; oring deleted -- it existed to amortize the vmcnt(0) drain that
// the lgkm-only barrier already removed).
__global__ __launch_bounds__(512) void lstm_scan_v15(
    const _Float16* __restrict__ pre_f, const _Float16* __restrict__ pre_b,
    const float* __restrict__ whh_f, const float* __restrict__ whh_b,
    _Float16* __restrict__ out)
{
    const int dir = blockIdx.x >> 6;
    const int b   = blockIdx.x & 63;
    const _Float16* __restrict__ pre = dir ? pre_b : pre_f;
    const float* __restrict__ w_hh   = dir ? whh_b : whh_f;

    const int tid = threadIdx.x;
    const int w   = tid >> 6;        // wave 0..7
    const int l   = tid & 63;
    const int jl  = l & 15;
    const int rg  = l >> 4;          // 0..3

    __shared__ _Float16 h_lds[2][HH];

    // B fragments: gate rows (cc*128 + w*16 + jl), k = kc*32 + rg*8 + e
    f16x8v bw[4][4];
    #pragma unroll
    for (int cc = 0; cc < 4; ++cc) {
        const float* wr_ = w_hh + (size_t)(cc * HH + w * 16 + jl) * HH + rg * 8;
        #pragma unroll
        for (int kc = 0; kc < 4; ++kc) {
            const float* p_ = wr_ + kc * 32;
            f16x8v f;
            #pragma unroll
            for (int e = 0; e < 8; ++e) f[e] = (_Float16)p_[e];
            bw[cc][kc] = f;
        }
    }

    if (tid < 2 * HH) ((_Float16*)h_lds)[tid] = (_Float16)0.f;

    // pre ring (f16 loads, converted): only lanes 0-15 consumed
    const size_t base = (size_t)b * TT * G4 + w * 16 + jl;
    float pf[PF][4];
    #pragma unroll
    for (int u = 0; u < PF; ++u) {
        int tau = dir ? (TT - 1 - u) : u;
        #pragma unroll
        for (int cc = 0; cc < 4; ++cc)
            pf[u][cc] = (float)pre[base + (size_t)tau * G4 + cc * HH];
    }

    float c = 0.f;
    const float ASIG = -1.4426950408889634f;  // -log2(e)
    const float ATAN =  2.8853900817779268f;  // 2*log2(e)

    __syncthreads();

    for (int s0 = 0; s0 < TT; s0 += PF) {
        #pragma unroll
        for (int u = 0; u < PF; ++u) {
            const int s = s0 + u;
            const int cur = u & 1;            // parity(s) == parity(u)

            // A fragments: wave-uniform per rg-group (rows replicate h)
            f16x8v a[4];
            #pragma unroll
            for (int kc = 0; kc < 4; ++kc)
                a[kc] = *(const f16x8v*)&h_lds[cur][kc * 32 + rg * 8];

            // C init from pre (row 0 real), pv captured BEFORE refill
            f32x4 acc[4];
            #pragma unroll
            for (int cc = 0; cc < 4; ++cc)
                acc[cc] = (f32x4){pf[u][cc], 0.f, 0.f, 0.f};

            // ring refill (clamped; loads survive across lgkm-only barriers)
            {
                int sn = s + PF;
                int taun = dir ? (TT - 1 - sn) : sn;
                taun = taun < 0 ? 0 : (taun > TT - 1 ? TT - 1 : taun);
                #pragma unroll
                for (int cc = 0; cc < 4; ++cc)
                    pf[u][cc] = (float)pre[base + (size_t)taun * G4 + cc * HH];
            }

            // 16 MFMA: G[gates of this wave] += Whh-chunk . h-chunk
            #pragma unroll
            for (int cc = 0; cc < 4; ++cc)
                #pragma unroll
                for (int kc = 0; kc < 4; ++kc)
                    acc[cc] = __builtin_amdgcn_mfma_f32_16x16x32_f16(
                        a[kc], bw[cc][kc], acc[cc], 0, 0, 0);

            // tail: lanes 0-15 hold cell (w*16+l): i,f,g,o in acc[cc][0]
            if (l < 16) {
                float gi = acc[0][0], gf = acc[1][0], gg = acc[2][0], go = acc[3][0];
                float ei = __builtin_amdgcn_exp2f(ASIG * gi);
                float si = __builtin_amdgcn_rcpf(1.f + ei);
                float ef = __builtin_amdgcn_exp2f(ASIG * gf);
                float sf = __builtin_amdgcn_rcpf(1.f + ef);
                float eg = __builtin_amdgcn_exp2f(ATAN * gg);
                float tg = 1.f - 2.f * __builtin_amdgcn_rcpf(1.f + eg);
                float eo = __builtin_amdgcn_exp2f(ASIG * go);
                float so = __builtin_amdgcn_rcpf(1.f + eo);
                c = fmaf(sf, c, si * tg);
                float e2 = __builtin_amdgcn_exp2f(ATAN * c);
                float hval = so * (1.f - 2.f * __builtin_amdgcn_rcpf(1.f + e2));
                int j = w * 16 + l;
                _Float16 h16 = (_Float16)hval;
                h_lds[cur ^ 1][j] = h16;
                int tau = dir ? (TT - 1 - s) : s;
                out[((size_t)b * TT + tau) * (2 * HH) + dir * HH + j] = h16;
            }
            barrier_lds_only();
        }
    }
}

// ---------------- FC v3: h2 f16, w_fc staged in LDS ----------------
__global__ __launch_bounds__(256) void fc_v3(
    const _Float16* __restrict__ h2, const float* __restrict__ w_fc,
    const float* __restrict__ b_fc, float* __restrict__ out)
{
    __shared__ float4 wsT[64][64];          // [k4][n]
    const int tid = threadIdx.x;
    const int bm  = blockIdx.x * 64;
    const int n   = tid & 63;
    const int mg  = tid >> 6;

    #pragma unroll
    for (int qq = 0; qq < 16; ++qq) {
        int id = qq * 256 + tid;
        int nn = id >> 6, k4 = id & 63;
        wsT[k4][nn] = *(const float4*)&w_fc[(size_t)nn * 256 + k4 * 4];
    }
    __syncthreads();

    const float bias = b_fc[n];
    const _Float16* hrow = h2 + (size_t)(bm + mg * 16) * 256;

    float acc[16];
    #pragma unroll
    for (int mi = 0; mi < 16; ++mi) acc[mi] = 0.f;

    #pragma unroll 2
    for (int k4 = 0; k4 < 64; ++k4) {
        float4 w4 = wsT[k4][n];
        #pragma unroll
        for (int mi = 0; mi < 16; ++mi) {
            f16x4v hv = *(const f16x4v*)(hrow + (size_t)mi * 256 + k4 * 4); // 8B uniform
            acc[mi] = fmaf((float)hv[0], w4.x, acc[mi]);
            acc[mi] = fmaf((float)hv[1], w4.y, acc[mi]);
            acc[mi] = fmaf((float)hv[2], w4.z, acc[mi]);
            acc[mi] = fmaf((float)hv[3], w4.w, acc[mi]);
        }
    }
    #pragma unroll
    for (int mi = 0; mi < 16; ++mi)
        out[(size_t)(bm + mg * 16 + mi) * 64 + n] = acc[mi] + bias;
}

extern "C" void kernel_launch(void* const* d_in, const int* in_sizes, int n_in,
                              void* d_out, int out_size, void* d_ws, size_t ws_size,
                              hipStream_t stream) {
    const float* x        = (const float*)d_in[0];
    const float* w_ih_l0  = (const float*)d_in[1];
    const float* w_hh_l0  = (const float*)d_in[2];
    const float* b_ih_l0  = (const float*)d_in[3];
    const float* b_hh_l0  = (const float*)d_in[4];
    const float* w_ih_l0r = (const float*)d_in[5];
    const float* w_hh_l0r = (const float*)d_in[6];
    const float* b_ih_l0r = (const float*)d_in[7];
    const float* b_hh_l0r = (const float*)d_in[8];
    const float* w_ih_l1  = (const float*)d_in[9];
    const float* w_hh_l1  = (const float*)d_in[10];
    const float* b_ih_l1  = (const float*)d_in[11];
    const float* b_hh_l1  = (const float*)d_in[12];
    const float* w_ih_l1r = (const float*)d_in[13];
    const float* w_hh_l1r = (const float*)d_in[14];
    const float* b_ih_l1r = (const float*)d_in[15];
    const float* b_hh_l1r = (const float*)d_in[16];
    const float* w_fc     = (const float*)d_in[17];
    const float* b_fc     = (const float*)d_in[18];

    // all-f16 scratch layout in d_ws (~105 MB total)
    _Float16* wsh    = (_Float16*)d_ws;
    _Float16* preh_f = wsh;                      // 16,777,216 f16
    _Float16* preh_b = preh_f + 16777216;        // 16,777,216
    _Float16* out0h  = preh_b + 16777216;        //  8,388,608
    _Float16* out1h  = out0h  + 8388608;         //  8,388,608
    _Float16* xf16   = out1h  + 8388608;         //  2,097,152
    _Float16* w0f    = xf16   + 2097152;         //     32,768
    _Float16* w0r    = w0f    + 32768;
    _Float16* w1f    = w0r    + 32768;           //    131,072
    _Float16* w1r    = w1f    + 131072;

    dim3 gg(256, 4);  // M/128 x 512/128

    // weight + x converts (inputs const -> all up front)
    convert_f16<<<32,   256, 0, stream>>>((const float4*)w_ih_l0,  (f16x4v*)w0f, 8192);
    convert_f16<<<32,   256, 0, stream>>>((const float4*)w_ih_l0r, (f16x4v*)w0r, 8192);
    convert_f16<<<128,  256, 0, stream>>>((const float4*)w_ih_l1,  (f16x4v*)w1f, 32768);
    convert_f16<<<128,  256, 0, stream>>>((const float4*)w_ih_l1r, (f16x4v*)w1r, 32768);
    convert_f16<<<2048, 256, 0, stream>>>((const float4*)x, (f16x4v*)xf16, 524288);

    // Layer 0
    gemm_f16<64><<<gg, 256, 0, stream>>>(xf16, w0f, b_ih_l0,  b_hh_l0,  preh_f);
    gemm_f16<64><<<gg, 256, 0, stream>>>(xf16, w0r, b_ih_l0r, b_hh_l0r, preh_b);
    lstm_scan_v15<<<128, 512, 0, stream>>>(preh_f, preh_b, w_hh_l0, w_hh_l0r, out0h);

    // Layer 1 (consumes out0h f16 directly -- no convert)
    gemm_f16<256><<<gg, 256, 0, stream>>>(out0h, w1f, b_ih_l1,  b_hh_l1,  preh_f);
    gemm_f16<256><<<gg, 256, 0, stream>>>(out0h, w1r, b_ih_l1r, b_hh_l1r, preh_b);
    lstm_scan_v15<<<128, 512, 0, stream>>>(preh_f, preh_b, w_hh_l1, w_hh_l1r, out1h);

    // FC
    fc_v3<<<512, 256, 0, stream>>>(out1h, w_fc, b_fc, (float*)d_out);
}

// Round 20
// 553.716 us; speedup vs baseline: 1.4579x; 1.0328x over previous
//
#include <hip/hip_runtime.h>

#define TT 512   // sequence length
#define BB 64    // batch
#define HH 128   // hidden
#define G4 512   // 4*H
#define PF 4     // prefetch ring depth (even, divides TT)

typedef float f32x4  __attribute__((ext_vector_type(4)));
typedef _Float16 f16x4v __attribute__((ext_vector_type(4)));
typedef _Float16 f16x8v __attribute__((ext_vector_type(8)));

// barrier that waits ONLY on LDS (lgkmcnt) -- global loads/stores stay in flight
__device__ __forceinline__ void barrier_lds_only() {
    asm volatile("s_waitcnt lgkmcnt(0)\n\ts_barrier" ::: "memory");
}

// ---------------- merged fp32 -> fp16 convert: 5 segments, 1 launch ----------------
__global__ __launch_bounds__(256) void convert_all(
    const float4* __restrict__ s0, f16x4v* __restrict__ d0, int n0,
    const float4* __restrict__ s1, f16x4v* __restrict__ d1, int n1,
    const float4* __restrict__ s2, f16x4v* __restrict__ d2, int n2,
    const float4* __restrict__ s3, f16x4v* __restrict__ d3, int n3,
    const float4* __restrict__ s4, f16x4v* __restrict__ d4, int n4)
{
    const int tid0 = blockIdx.x * 256 + threadIdx.x;
    const int strd = gridDim.x * 256;
    #define CVT(S, D, N)                                            \
        for (int i = tid0; i < (N); i += strd) {                    \
            float4 f = (S)[i];                                      \
            f16x4v h;                                               \
            h[0] = (_Float16)f.x; h[1] = (_Float16)f.y;             \
            h[2] = (_Float16)f.z; h[3] = (_Float16)f.w;             \
            (D)[i] = h;                                             \
        }
    CVT(s0, d0, n0)
    CVT(s1, d1, n1)
    CVT(s2, d2, n2)
    CVT(s3, d3, n3)
    CVT(s4, d4, n4)
    #undef CVT
}

// ---------------- f16 pre-GEMM, fwd+bwd fused via blockIdx.z ----------------
// pre[m,n] = sum_k A[m,k]W[n,k] + b0[n]+b1[n]; A,W,C f16. Tile 128x128, KC=32.
template<int K>
__global__ __launch_bounds__(256) void gemm_f16z(
    const _Float16* __restrict__ Af,
    const _Float16* __restrict__ Wf0, const _Float16* __restrict__ Wf1,
    const float* __restrict__ b0f, const float* __restrict__ b1f,
    const float* __restrict__ b0r, const float* __restrict__ b1r,
    _Float16* __restrict__ C0, _Float16* __restrict__ C1)
{
    const int z = blockIdx.z;
    const _Float16* __restrict__ Wf = z ? Wf1 : Wf0;
    const float* __restrict__ b0 = z ? b0r : b0f;
    const float* __restrict__ b1 = z ? b1r : b1f;
    _Float16* __restrict__ C = z ? C1 : C0;

    constexpr int NC  = K / 32;
    constexpr int LDA = 40;                  // f16 per staged row (32 + 8 pad)
    __shared__ _Float16 As[128 * LDA];
    __shared__ _Float16 Ws[128 * LDA];

    const int bm  = blockIdx.x * 128;
    const int bn  = blockIdx.y * 128;
    const int tid = threadIdx.x;
    const int wv  = tid >> 6;
    const int l   = tid & 63;
    const int jl  = l & 15;
    const int rg  = l >> 4;
    const int wr  = wv >> 1;
    const int wc  = wv & 1;

    const int sr = tid >> 1;
    const int sc = (tid & 1) * 16;

    const _Float16* Ap = Af + (size_t)(bm + sr) * K + sc;
    const _Float16* Wp = Wf + (size_t)(bn + sr) * K + sc;

    f32x4 acc[4][4];
    #pragma unroll
    for (int i = 0; i < 4; ++i)
        #pragma unroll
        for (int j = 0; j < 4; ++j)
            acc[i][j] = (f32x4){0.f, 0.f, 0.f, 0.f};

    f16x8v pa[2], pw[2];
    pa[0] = *(const f16x8v*)(Ap);     pa[1] = *(const f16x8v*)(Ap + 8);
    pw[0] = *(const f16x8v*)(Wp);     pw[1] = *(const f16x8v*)(Wp + 8);

    #pragma unroll 1
    for (int c = 0; c < NC; ++c) {
        __syncthreads();
        {
            int off = sr * LDA + sc;
            *(f16x8v*)&As[off]     = pa[0];
            *(f16x8v*)&As[off + 8] = pa[1];
            *(f16x8v*)&Ws[off]     = pw[0];
            *(f16x8v*)&Ws[off + 8] = pw[1];
        }
        __syncthreads();
        if (c + 1 < NC) {
            pa[0] = *(const f16x8v*)(Ap + (c + 1) * 32);
            pa[1] = *(const f16x8v*)(Ap + (c + 1) * 32 + 8);
            pw[0] = *(const f16x8v*)(Wp + (c + 1) * 32);
            pw[1] = *(const f16x8v*)(Wp + (c + 1) * 32 + 8);
        }
        f16x8v ah[4], wh[4];
        #pragma unroll
        for (int t = 0; t < 4; ++t) {
            ah[t] = *(const f16x8v*)&As[(wr * 64 + t * 16 + jl) * LDA + rg * 8];
            wh[t] = *(const f16x8v*)&Ws[(wc * 64 + t * 16 + jl) * LDA + rg * 8];
        }
        #pragma unroll
        for (int tm = 0; tm < 4; ++tm)
            #pragma unroll
            for (int tn = 0; tn < 4; ++tn)
                acc[tm][tn] = __builtin_amdgcn_mfma_f32_16x16x32_f16(
                    ah[tm], wh[tn], acc[tm][tn], 0, 0, 0);
    }

    // epilogue: C layout col=lane&15 (n), row=(lane>>4)*4+r (m); f16 stores
    #pragma unroll
    for (int tn = 0; tn < 4; ++tn) {
        int n = bn + wc * 64 + tn * 16 + jl;
        float bias = b0[n] + b1[n];
        #pragma unroll
        for (int tm = 0; tm < 4; ++tm) {
            int m = bm + wr * 64 + tm * 16 + rg * 4;
            #pragma unroll
            for (int r = 0; r < 4; ++r)
                C[(size_t)(m + r) * G4 + n] = (_Float16)(acc[tm][tn][r] + bias);
        }
    }
}

// ---------------- LSTM scan v15 (R19-proven: 245 us, absmax 9.77e-4) ----------
__global__ __launch_bounds__(512) void lstm_scan_v15(
    const _Float16* __restrict__ pre_f, const _Float16* __restrict__ pre_b,
    const float* __restrict__ whh_f, const float* __restrict__ whh_b,
    _Float16* __restrict__ out)
{
    const int dir = blockIdx.x >> 6;
    const int b   = blockIdx.x & 63;
    const _Float16* __restrict__ pre = dir ? pre_b : pre_f;
    const float* __restrict__ w_hh   = dir ? whh_b : whh_f;

    const int tid = threadIdx.x;
    const int w   = tid >> 6;        // wave 0..7
    const int l   = tid & 63;
    const int jl  = l & 15;
    const int rg  = l >> 4;          // 0..3

    __shared__ _Float16 h_lds[2][HH];

    // B fragments: gate rows (cc*128 + w*16 + jl), k = kc*32 + rg*8 + e
    f16x8v bw[4][4];
    #pragma unroll
    for (int cc = 0; cc < 4; ++cc) {
        const float* wr_ = w_hh + (size_t)(cc * HH + w * 16 + jl) * HH + rg * 8;
        #pragma unroll
        for (int kc = 0; kc < 4; ++kc) {
            const float* p_ = wr_ + kc * 32;
            f16x8v f;
            #pragma unroll
            for (int e = 0; e < 8; ++e) f[e] = (_Float16)p_[e];
            bw[cc][kc] = f;
        }
    }

    if (tid < 2 * HH) ((_Float16*)h_lds)[tid] = (_Float16)0.f;

    // pre ring (f16 loads): only lanes 0-15 consumed
    const size_t base = (size_t)b * TT * G4 + w * 16 + jl;
    float pf[PF][4];
    #pragma unroll
    for (int u = 0; u < PF; ++u) {
        int tau = dir ? (TT - 1 - u) : u;
        #pragma unroll
        for (int cc = 0; cc < 4; ++cc)
            pf[u][cc] = (float)pre[base + (size_t)tau * G4 + cc * HH];
    }

    float c = 0.f;
    const float ASIG = -1.4426950408889634f;  // -log2(e)
    const float ATAN =  2.8853900817779268f;  // 2*log2(e)

    __syncthreads();

    for (int s0 = 0; s0 < TT; s0 += PF) {
        #pragma unroll
        for (int u = 0; u < PF; ++u) {
            const int s = s0 + u;
            const int cur = u & 1;            // parity(s) == parity(u)

            // A fragments: wave-uniform per rg-group
            f16x8v a[4];
            #pragma unroll
            for (int kc = 0; kc < 4; ++kc)
                a[kc] = *(const f16x8v*)&h_lds[cur][kc * 32 + rg * 8];

            // C init from pre (row 0 real), pv captured BEFORE refill
            f32x4 acc[4];
            #pragma unroll
            for (int cc = 0; cc < 4; ++cc)
                acc[cc] = (f32x4){pf[u][cc], 0.f, 0.f, 0.f};

            // ring refill (clamped; loads survive across lgkm-only barriers)
            {
                int sn = s + PF;
                int taun = dir ? (TT - 1 - sn) : sn;
                taun = taun < 0 ? 0 : (taun > TT - 1 ? TT - 1 : taun);
                #pragma unroll
                for (int cc = 0; cc < 4; ++cc)
                    pf[u][cc] = (float)pre[base + (size_t)taun * G4 + cc * HH];
            }

            // 16 MFMA: G[gates of this wave] += Whh-chunk . h-chunk
            #pragma unroll
            for (int cc = 0; cc < 4; ++cc)
                #pragma unroll
                for (int kc = 0; kc < 4; ++kc)
                    acc[cc] = __builtin_amdgcn_mfma_f32_16x16x32_f16(
                        a[kc], bw[cc][kc], acc[cc], 0, 0, 0);

            // tail: lanes 0-15 hold cell (w*16+l): i,f,g,o in acc[cc][0]
            if (l < 16) {
                float gi = acc[0][0], gf = acc[1][0], gg = acc[2][0], go = acc[3][0];
                float ei = __builtin_amdgcn_exp2f(ASIG * gi);
                float si = __builtin_amdgcn_rcpf(1.f + ei);
                float ef = __builtin_amdgcn_exp2f(ASIG * gf);
                float sf = __builtin_amdgcn_rcpf(1.f + ef);
                float eg = __builtin_amdgcn_exp2f(ATAN * gg);
                float tg = 1.f - 2.f * __builtin_amdgcn_rcpf(1.f + eg);
                float eo = __builtin_amdgcn_exp2f(ASIG * go);
                float so = __builtin_amdgcn_rcpf(1.f + eo);
                c = fmaf(sf, c, si * tg);
                float e2 = __builtin_amdgcn_exp2f(ATAN * c);
                float hval = so * (1.f - 2.f * __builtin_amdgcn_rcpf(1.f + e2));
                int j = w * 16 + l;
                _Float16 h16 = (_Float16)hval;
                h_lds[cur ^ 1][j] = h16;
                int tau = dir ? (TT - 1 - s) : s;
                out[((size_t)b * TT + tau) * (2 * HH) + dir * HH + j] = h16;
            }
            barrier_lds_only();
        }
    }
}

// ---------------- FC v3: h2 f16, w_fc staged in LDS (R19-proven) ----------------
__global__ __launch_bounds__(256) void fc_v3(
    const _Float16* __restrict__ h2, const float* __restrict__ w_fc,
    const float* __restrict__ b_fc, float* __restrict__ out)
{
    __shared__ float4 wsT[64][64];          // [k4][n]
    const int tid = threadIdx.x;
    const int bm  = blockIdx.x * 64;
    const int n   = tid & 63;
    const int mg  = tid >> 6;

    #pragma unroll
    for (int qq = 0; qq < 16; ++qq) {
        int id = qq * 256 + tid;
        int nn = id >> 6, k4 = id & 63;
        wsT[k4][nn] = *(const float4*)&w_fc[(size_t)nn * 256 + k4 * 4];
    }
    __syncthreads();

    const float bias = b_fc[n];
    const _Float16* hrow = h2 + (size_t)(bm + mg * 16) * 256;

    float acc[16];
    #pragma unroll
    for (int mi = 0; mi < 16; ++mi) acc[mi] = 0.f;

    #pragma unroll 2
    for (int k4 = 0; k4 < 64; ++k4) {
        float4 w4 = wsT[k4][n];
        #pragma unroll
        for (int mi = 0; mi < 16; ++mi) {
            f16x4v hv = *(const f16x4v*)(hrow + (size_t)mi * 256 + k4 * 4);
            acc[mi] = fmaf((float)hv[0], w4.x, acc[mi]);
            acc[mi] = fmaf((float)hv[1], w4.y, acc[mi]);
            acc[mi] = fmaf((float)hv[2], w4.z, acc[mi]);
            acc[mi] = fmaf((float)hv[3], w4.w, acc[mi]);
        }
    }
    #pragma unroll
    for (int mi = 0; mi < 16; ++mi)
        out[(size_t)(bm + mg * 16 + mi) * 64 + n] = acc[mi] + bias;
}

extern "C" void kernel_launch(void* const* d_in, const int* in_sizes, int n_in,
                              void* d_out, int out_size, void* d_ws, size_t ws_size,
                              hipStream_t stream) {
    const float* x        = (const float*)d_in[0];
    const float* w_ih_l0  = (const float*)d_in[1];
    const float* w_hh_l0  = (const float*)d_in[2];
    const float* b_ih_l0  = (const float*)d_in[3];
    const float* b_hh_l0  = (const float*)d_in[4];
    const float* w_ih_l0r = (const float*)d_in[5];
    const float* w_hh_l0r = (const float*)d_in[6];
    const float* b_ih_l0r = (const float*)d_in[7];
    const float* b_hh_l0r = (const float*)d_in[8];
    const float* w_ih_l1  = (const float*)d_in[9];
    const float* w_hh_l1  = (const float*)d_in[10];
    const float* b_ih_l1  = (const float*)d_in[11];
    const float* b_hh_l1  = (const float*)d_in[12];
    const float* w_ih_l1r = (const float*)d_in[13];
    const float* w_hh_l1r = (const float*)d_in[14];
    const float* b_ih_l1r = (const float*)d_in[15];
    const float* b_hh_l1r = (const float*)d_in[16];
    const float* w_fc     = (const float*)d_in[17];
    const float* b_fc     = (const float*)d_in[18];

    // all-f16 scratch layout in d_ws (~105 MB total)
    _Float16* wsh    = (_Float16*)d_ws;
    _Float16* preh_f = wsh;                      // 16,777,216 f16
    _Float16* preh_b = preh_f + 16777216;        // 16,777,216
    _Float16* out0h  = preh_b + 16777216;        //  8,388,608
    _Float16* out1h  = out0h  + 8388608;         //  8,388,608
    _Float16* xf16   = out1h  + 8388608;         //  2,097,152
    _Float16* w0f    = xf16   + 2097152;         //     32,768
    _Float16* w0r    = w0f    + 32768;
    _Float16* w1f    = w0r    + 32768;           //    131,072
    _Float16* w1r    = w1f    + 131072;

    dim3 gg(256, 4, 2);  // M/128 x 512/128 x {fwd,bwd}

    // all converts in ONE launch (inputs const -> up front)
    convert_all<<<1024, 256, 0, stream>>>(
        (const float4*)x,         (f16x4v*)xf16, 524288,
        (const float4*)w_ih_l0,   (f16x4v*)w0f,  8192,
        (const float4*)w_ih_l0r,  (f16x4v*)w0r,  8192,
        (const float4*)w_ih_l1,   (f16x4v*)w1f,  32768,
        (const float4*)w_ih_l1r,  (f16x4v*)w1r,  32768);

    // Layer 0: fwd+bwd gemm in one launch
    gemm_f16z<64><<<gg, 256, 0, stream>>>(xf16, w0f, w0r,
        b_ih_l0, b_hh_l0, b_ih_l0r, b_hh_l0r, preh_f, preh_b);
    lstm_scan_v15<<<128, 512, 0, stream>>>(preh_f, preh_b, w_hh_l0, w_hh_l0r, out0h);

    // Layer 1
    gemm_f16z<256><<<gg, 256, 0, stream>>>(out0h, w1f, w1r,
        b_ih_l1, b_hh_l1, b_ih_l1r, b_hh_l1r, preh_f, preh_b);
    lstm_scan_v15<<<128, 512, 0, stream>>>(preh_f, preh_b, w_hh_l1, w_hh_l1r, out1h);

    // FC
    fc_v3<<<512, 256, 0, stream>>>(out1h, w_fc, b_fc, (float*)d_out);
}